// Round 7
// baseline (199.451 us; speedup 1.0000x reference)
//
#include <hip/hip_runtime.h>
#include <math.h>

// Problem dims (fixed by setup_inputs)
#define BBATCH 8
#define TT    4096
#define II    64
#define DD    128
#define OO    64
#define PP    8
#define NTOT  (BBATCH * TT)      // 32768
#define RPB   64                 // rows per block == scan chunk
#define NBLK  (NTOT / RPB)       // 512 blocks; must equal resident capacity
#define CPB   (TT / RPB)         // 64 chunks per batch

// LDS layout (bytes); regions reused across time-disjoint phases
#define PAN_H  0                 // h panel: 128 cols x 136 B (64 rows bf16 + pad)
#define PAN_Z  17408             // z panel: same
#define WBUF   34816             // phase A: W chunk 64 x 64 B
#define AGGLS  34816             // post-GEMM: 128 f32 aggregates (overlays WBUF)
#define HTB    34816             // scan: 64 rows x 132 B bf16 (overlays, post-agg)
#define VTBUF  38912             // phase A: Vt chunk 256 x 64 B
#define OT0    55296             // Ot buf0 (staged during scan)
#define OT1    0                 // phase C: Ot buf1 over dead h-panel
#define W2BUF  8192              // phase C: W2 dbuf 2 x 8192 over dead panels
#define LDSSZ  63488             // => 2 blocks/CU by LDS; grid 512 all-resident

typedef short bf16x8 __attribute__((ext_vector_type(8)));
typedef float f32x4  __attribute__((ext_vector_type(4)));

__device__ __forceinline__ unsigned short f2bf(float f) {
    union { float f; unsigned int u; } v; v.f = f;
    unsigned int r = v.u + 0x7fffu + ((v.u >> 16) & 1u);   // RNE
    return (unsigned short)(r >> 16);
}

__device__ __forceinline__ float bf2f(unsigned short b) {
    union { float f; unsigned int u; } v; v.u = ((unsigned int)b) << 16;
    return v.f;
}

__device__ __forceinline__ void gload_lds16(const void* g, void* l) {
    __builtin_amdgcn_global_load_lds(
        (const __attribute__((address_space(1))) unsigned int*)g,
        (__attribute__((address_space(3))) unsigned int*)l, 16, 0, 0);
}

// pack the 8 piecewise-linear knot weights for one scalar into 4 dwords (8 bf16)
__device__ __forceinline__ uint4 apl_w_pack(float xv) {
    float t = fminf(fmaxf((xv + 1.0f) * 3.5f, 0.0f), 7.0f);
    int idx = (int)t; if (idx > 6) idx = 6;
    float frac = t - (float)idx;
    const unsigned int b0 = f2bf(1.0f - frac);
    const unsigned int b1 = f2bf(frac);
    const int q = idx >> 1;
    const bool odd = (idx & 1) != 0;
    const unsigned int vA = odd ? (b0 << 16) : (b0 | (b1 << 16));
    const unsigned int vB = odd ? b1 : 0u;
    uint4 w;
    w.x = (q == 0) ? vA : 0u;
    w.y = (q == 1) ? vA : ((q == 0) ? vB : 0u);
    w.z = (q == 2) ? vA : ((q == 1) ? vB : 0u);
    w.w = (q == 3) ? vA : ((q == 2) ? vB : 0u);
    return w;
}

// ---------------------------------------------------------------------------
// prep_tables: Vt[col][k] bf16 (256x512) from hv|zv; Ot[col][k] bf16 (64x1024)
// from ov.  Also zeroes the grid-barrier counter (d_ws is re-poisoned 0xAA
// before every timed call).
// ---------------------------------------------------------------------------
__global__ __launch_bounds__(256) void prep_tables(
    const float* __restrict__ hv, const float* __restrict__ zv,
    const float* __restrict__ ov,
    unsigned short* __restrict__ Vt, unsigned short* __restrict__ Ot,
    unsigned int* __restrict__ bar)
{
    const int b = blockIdx.x, tid = threadIdx.x;
    if (b == 0 && tid == 0) bar[0] = 0u;
    if (b < 512) {
        const int k = b, c = tid;
        float v = (c < 128) ? hv[(size_t)k * 128 + c] : zv[(size_t)k * 128 + (c - 128)];
        Vt[(size_t)c * 512 + k] = f2bf(v);
    } else {
        const int k = (b - 512) * 4 + (tid >> 6), c = tid & 63;
        Ot[(size_t)c * 1024 + k] = f2bf(ov[(size_t)k * 64 + c]);
    }
}

// ---------------------------------------------------------------------------
// Fused everything: APL1 GEMM -> aggregates -> grid barrier -> prefix ->
// in-LDS scan (ht) -> APL2 GEMM (y).  512 blocks x 256 threads, 2 blocks/CU.
// ---------------------------------------------------------------------------
__global__ __launch_bounds__(256, 2) void fused_all(
    const float* __restrict__ x, const float* __restrict__ h0,
    const unsigned short* __restrict__ Vt, const unsigned short* __restrict__ Ot,
    float* __restrict__ agg, unsigned int* __restrict__ bar,
    float* __restrict__ ht_out, float* __restrict__ y)
{
    __shared__ unsigned char smem[LDSSZ];
    const int tid = threadIdx.x;
    const int wave = tid >> 6, lane = tid & 63;
    const int g = blockIdx.x;            // chunk id
    const int n0 = g * RPB;
    const int b = g >> 6, lb = g & 63;

    // ---------------- Phase A: C(64 x 256) = W(64 x 512) x Vt^T -------------
    // preload this thread's 16 x-values (thread = (n = tid>>2, ib = tid&3))
    float xs[16];
    {
        const float* xp = x + (size_t)(n0 + (tid >> 2)) * II + (tid & 3);
        #pragma unroll
        for (int c = 0; c < 16; ++c) xs[c] = xp[4 * c];
    }

    const int colbase = wave * 64;       // waves 0,1: h cols; 2,3: z cols
    f32x4 acc[4][4];
    #pragma unroll
    for (int tr = 0; tr < 4; ++tr)
        #pragma unroll
        for (int tc = 0; tc < 4; ++tc)
            acc[tr][tc] = (f32x4){0.f, 0.f, 0.f, 0.f};

    const int u = lane >> 4;             // k-position 0..3 (x8 bf16)

    for (int c = 0; c < 16; ++c) {
        __syncthreads();                 // previous chunk's LDS reads retired
        // stage Vt chunk c: 256 cols x 64 B
        #pragma unroll
        for (int j = 0; j < 4; ++j) {
            const int r0 = wave * 64 + j * 16;
            const int r = r0 + (lane >> 2);
            const int ug = (lane & 3) ^ ((r >> 2) & 3);
            gload_lds16((const unsigned char*)Vt + (size_t)r * 1024 + c * 64 + ug * 16,
                        smem + VTBUF + r0 * 64);
        }
        // build W chunk c: 64 rows x 64 B (i = 4c + ib)
        {
            const int n = tid >> 2, ib = tid & 3;
            uint4 w = apl_w_pack(xs[c]);
            *(uint4*)(smem + WBUF + n * 64 + ((ib ^ (n & 3)) * 16)) = w;
        }
        __syncthreads();                 // staging + W visible (drains DMA)

        bf16x8 a[4], bb[4];
        #pragma unroll
        for (int tr = 0; tr < 4; ++tr) {
            const int r = tr * 16 + (lane & 15);
            a[tr] = *(const bf16x8*)(smem + WBUF + r * 64 + ((u ^ (r & 3)) * 16));
        }
        #pragma unroll
        for (int tc = 0; tc < 4; ++tc) {
            const int rc = colbase + tc * 16 + (lane & 15);
            bb[tc] = *(const bf16x8*)(smem + VTBUF + rc * 64 + ((u ^ ((rc >> 2) & 3)) * 16));
        }
        #pragma unroll
        for (int tr = 0; tr < 4; ++tr)
            #pragma unroll
            for (int tc = 0; tc < 4; ++tc)
                acc[tr][tc] = __builtin_amdgcn_mfma_f32_16x16x32_bf16(a[tr], bb[tc], acc[tr][tc], 0, 0, 0);
    }
    __syncthreads();                     // WBUF/VTBUF retire -> AGGLS reuse ok

    // aggregates (waves 0,1 hold h cols 0..127) -> LDS
    if (wave < 2) {
        #pragma unroll
        for (int tc = 0; tc < 4; ++tc) {
            float s = 0.0f;
            #pragma unroll
            for (int tr = 0; tr < 4; ++tr) {
                f32x4 v = acc[tr][tc];
                s += v[0] + v[1] + v[2] + v[3];
            }
            s += __shfl_xor(s, 16);
            s += __shfl_xor(s, 32);
            if ((lane >> 4) == 0)
                *(float*)(smem + AGGLS + (colbase + tc * 16 + lane) * 4) = s;
        }
    }

    // panels: C/D layout col=lane&15 (+tile), row=(lane>>4)*4+reg (+tile)
    #pragma unroll
    for (int tr = 0; tr < 4; ++tr) {
        #pragma unroll
        for (int tc = 0; tc < 4; ++tc) {
            const int col = colbase + tc * 16 + (lane & 15);
            const int r0 = tr * 16 + (lane >> 4) * 4;
            f32x4 v = acc[tr][tc];
            ushort4 p4;
            if (col < 128) {
                p4.x = f2bf(v[0]); p4.y = f2bf(v[1]);
                p4.z = f2bf(v[2]); p4.w = f2bf(v[3]);
                *(ushort4*)(smem + PAN_H + col * 136 + r0 * 2) = p4;
            } else {
                p4.x = f2bf(1.0f / (1.0f + __expf(-v[0])));
                p4.y = f2bf(1.0f / (1.0f + __expf(-v[1])));
                p4.z = f2bf(1.0f / (1.0f + __expf(-v[2])));
                p4.w = f2bf(1.0f / (1.0f + __expf(-v[3])));
                *(ushort4*)(smem + PAN_Z + (col - 128) * 136 + r0 * 2) = p4;
            }
        }
    }

    // kick off Ot chunk-0 DMA (overlaps barrier/prefix/scan)
    #pragma unroll
    for (int j = 0; j < 2; ++j) {
        const int r0 = wave * 16 + j * 8;
        const int r = r0 + (lane >> 3);
        const int ug = (lane & 7) ^ (r & 7);
        gload_lds16((const unsigned char*)Ot + (size_t)r * 2048 + ug * 16,
                    smem + OT0 + r0 * 128);
    }

    // publish this chunk's aggregate to global (plain stores + fence)
    if (tid < 128)
        agg[(size_t)g * 128 + tid] = *(const float*)(smem + AGGLS + tid * 4);
    __threadfence();
    __syncthreads();                     // all publishes done before arrive

    // ---------------- grid barrier (all 512 blocks resident) ----------------
    if (tid == 0) {
        atomicAdd(bar, 1u);
        while (atomicAdd(bar, 0u) < (unsigned)NBLK) __builtin_amdgcn_s_sleep(2);
    }
    __syncthreads();
    __threadfence();                     // acquire

    // ---------------- prefix + in-LDS z-mix scan -> ht ----------------------
    if (tid < 128) {
        const int d = tid;
        float run = h0[(size_t)b * 128 + d];
        const float* ap = agg + (size_t)(g - lb) * 128 + d;
        for (int k = 0; k < lb; ++k) run += ap[(size_t)k * 128];
        #pragma unroll
        for (int rq = 0; rq < 16; ++rq) {
            ushort4 h4 = *(const ushort4*)(smem + PAN_H + d * 136 + rq * 8);
            ushort4 z4 = *(const ushort4*)(smem + PAN_Z + d * 136 + rq * 8);
            const unsigned short* hp = (const unsigned short*)&h4;
            const unsigned short* zp = (const unsigned short*)&z4;
            #pragma unroll
            for (int k = 0; k < 4; ++k) {
                const int r = rq * 4 + k;
                float hb = bf2f(hp[k]);
                float zt = bf2f(zp[k]);
                run += hb;
                float htv = (1.0f - zt) * run + zt * hb;
                ht_out[(size_t)(n0 + r) * DD + d] = htv;
                *(unsigned short*)(smem + HTB + r * 132 + d * 2) = f2bf(htv);
            }
        }
    }
    __syncthreads();                     // htb ready; OT0 DMA drained; panels dead

    // ---------------- Phase C: y(64 x 64) = W2(64 x 1024) x Ot^T ------------
    auto stageOt = [&](int c, unsigned char* buf) {
        #pragma unroll
        for (int j = 0; j < 2; ++j) {
            const int r0 = wave * 16 + j * 8;
            const int r = r0 + (lane >> 3);
            const int ug = (lane & 7) ^ (r & 7);
            gload_lds16((const unsigned char*)Ot + (size_t)r * 2048 + c * 128 + ug * 16,
                        buf + r0 * 128);
        }
    };
    auto buildW2 = [&](int c, int bi) {
        unsigned char* wb = smem + W2BUF + bi * 8192;
        const int n = tid >> 2, dl2 = tid & 3;
        unsigned int pair = *(const unsigned int*)(smem + HTB + n * 132 + (c * 8 + 2 * dl2) * 2);
        uint4 w0 = apl_w_pack(bf2f((unsigned short)(pair & 0xffffu)));
        uint4 w1 = apl_w_pack(bf2f((unsigned short)(pair >> 16)));
        *(uint4*)(wb + n * 128 + (((2 * dl2)     ^ (n & 7)) * 16)) = w0;
        *(uint4*)(wb + n * 128 + (((2 * dl2 + 1) ^ (n & 7)) * 16)) = w1;
    };

    buildW2(0, 0);
    __syncthreads();

    const int wr = wave >> 1, wc = wave & 1;
    f32x4 acc2[2][2];
    #pragma unroll
    for (int tr = 0; tr < 2; ++tr)
        #pragma unroll
        for (int tc = 0; tc < 2; ++tc)
            acc2[tr][tc] = (f32x4){0.f, 0.f, 0.f, 0.f};

    for (int c = 0; c < 16; ++c) {
        if (c < 15) {
            stageOt(c + 1, smem + (((c + 1) & 1) ? OT1 : OT0));
            buildW2(c + 1, (c + 1) & 1);
        }
        unsigned char* wb = smem + W2BUF + (c & 1) * 8192;
        unsigned char* ob = smem + ((c & 1) ? OT1 : OT0);
        #pragma unroll
        for (int s = 0; s < 2; ++s) {
            const int pos = s * 4 + (lane >> 4);
            bf16x8 a2[2], b2[2];
            #pragma unroll
            for (int tr = 0; tr < 2; ++tr) {
                const int r = wr * 32 + tr * 16 + (lane & 15);
                a2[tr] = *(const bf16x8*)(wb + r * 128 + ((pos ^ (r & 7)) * 16));
            }
            #pragma unroll
            for (int tc = 0; tc < 2; ++tc) {
                const int rc = wc * 32 + tc * 16 + (lane & 15);
                b2[tc] = *(const bf16x8*)(ob + rc * 128 + ((pos ^ (rc & 7)) * 16));
            }
            #pragma unroll
            for (int tr = 0; tr < 2; ++tr)
                #pragma unroll
                for (int tc = 0; tc < 2; ++tc)
                    acc2[tr][tc] = __builtin_amdgcn_mfma_f32_16x16x32_bf16(a2[tr], b2[tc], acc2[tr][tc], 0, 0, 0);
        }
        __syncthreads();
    }

    #pragma unroll
    for (int tr = 0; tr < 2; ++tr)
        #pragma unroll
        for (int tc = 0; tc < 2; ++tc) {
            const int col = wc * 32 + tc * 16 + (lane & 15);
            const int n = n0 + wr * 32 + tr * 16 + (lane >> 4) * 4;
            f32x4 v = acc2[tr][tc];
            #pragma unroll
            for (int rg = 0; rg < 4; ++rg)
                y[(size_t)(n + rg) * OO + col] = v[rg];
        }
}

// ---------------------------------------------------------------------------
extern "C" void kernel_launch(void* const* d_in, const int* in_sizes, int n_in,
                              void* d_out, int out_size, void* d_ws, size_t ws_size,
                              hipStream_t stream) {
    const float* x  = (const float*)d_in[0];   // (B,T,I)
    const float* h0 = (const float*)d_in[1];   // (B,D)
    const float* zv = (const float*)d_in[2];   // (I,P,D)
    const float* hv = (const float*)d_in[3];   // (I,P,D)
    const float* ov = (const float*)d_in[4];   // (D,P,O)

    float* y  = (float*)d_out;                           // (B,T,O)
    float* ht = (float*)d_out + (size_t)NTOT * OO;       // (B,T,D)

    unsigned int* bar = (unsigned int*)d_ws;                      // 64 B
    float* agg = (float*)((char*)d_ws + 64);                      // 512*128 f32
    unsigned short* Vt = (unsigned short*)(agg + (size_t)NBLK * 128);  // 256x512
    unsigned short* Ot = Vt + 256 * 512;                               // 64x1024

    prep_tables<<<768, 256, 0, stream>>>(hv, zv, ov, Vt, Ot, bar);
    fused_all<<<NBLK, 256, 0, stream>>>(x, h0, Vt, Ot, agg, bar, ht, y);
}

// Round 9
// 126.634 us; speedup vs baseline: 1.5750x; 1.5750x over previous
//
#include <hip/hip_runtime.h>
#include <math.h>

// Problem dims (fixed by setup_inputs)
#define BBATCH 8
#define TT    4096
#define II    64
#define DD    128
#define OO    64
#define PP    8
#define NTOT  (BBATCH * TT)      // 32768
#define RPB   64                 // rows per block == scan chunk
#define NBLK  (NTOT / RPB)       // 512 blocks; == resident capacity (2/CU)

// LDS layout (bytes); regions reused across time-disjoint phases
#define PAN_H  0                 // h panel: 128 cols x 136 B (64 rows bf16 + pad)
#define PAN_Z  17408             // z panel: same (ends 34816)
#define WBUF   34816             // phase A: W dbuf 2 x 5120 (64 rows x 80 B padded)
#define VTBUF  45056             // phase A: Vt dbuf 2 x 16384 (ends 77824)
#define HTB    45056             // scan: 64 rows x 264 B bf16 (!) over dead VTBUF, ends 61952
#define OT0    61952             // phase C: Ot buf0 (staged during poll/scan), ends 70144
#define OT1    70144             // phase C: Ot buf1, ends 78336
#define W2BUF  0                 // phase C: W2 dbuf 2 x 8192 over dead panels
#define LDSSZ  78336             // <= 81920 -> 2 blocks/CU -> grid 512 resident

typedef short bf16x8 __attribute__((ext_vector_type(8)));
typedef float f32x4  __attribute__((ext_vector_type(4)));

__device__ __forceinline__ unsigned short f2bf(float f) {
    union { float f; unsigned int u; } v; v.f = f;
    unsigned int r = v.u + 0x7fffu + ((v.u >> 16) & 1u);   // RNE
    return (unsigned short)(r >> 16);
}

__device__ __forceinline__ float bf2f(unsigned short b) {
    union { float f; unsigned int u; } v; v.u = ((unsigned int)b) << 16;
    return v.f;
}

__device__ __forceinline__ void gload_lds16(const void* g, void* l) {
    __builtin_amdgcn_global_load_lds(
        (const __attribute__((address_space(1))) unsigned int*)g,
        (__attribute__((address_space(3))) unsigned int*)l, 16, 0, 0);
}

// pack the 8 piecewise-linear knot weights for one scalar into 4 dwords (8 bf16)
__device__ __forceinline__ uint4 apl_w_pack(float xv) {
    float t = fminf(fmaxf((xv + 1.0f) * 3.5f, 0.0f), 7.0f);
    int idx = (int)t; if (idx > 6) idx = 6;
    float frac = t - (float)idx;
    const unsigned int b0 = f2bf(1.0f - frac);
    const unsigned int b1 = f2bf(frac);
    const int q = idx >> 1;
    const bool odd = (idx & 1) != 0;
    const unsigned int vA = odd ? (b0 << 16) : (b0 | (b1 << 16));
    const unsigned int vB = odd ? b1 : 0u;
    uint4 w;
    w.x = (q == 0) ? vA : 0u;
    w.y = (q == 1) ? vA : ((q == 0) ? vB : 0u);
    w.z = (q == 2) ? vA : ((q == 1) ? vB : 0u);
    w.w = (q == 3) ? vA : ((q == 2) ? vB : 0u);
    return w;
}

// ---------------------------------------------------------------------------
// prep_tables: Vt[col][k] bf16 (256x512) from hv|zv; Ot[col][k] bf16 (64x1024)
// from ov.  Blocks 512..575 also zero the 512 lookback flags.
// ---------------------------------------------------------------------------
__global__ __launch_bounds__(256) void prep_tables(
    const float* __restrict__ hv, const float* __restrict__ zv,
    const float* __restrict__ ov,
    unsigned short* __restrict__ Vt, unsigned short* __restrict__ Ot,
    unsigned int* __restrict__ flags)
{
    const int b = blockIdx.x, tid = threadIdx.x;
    if (b < 512) {
        const int k = b, c = tid;
        float v = (c < 128) ? hv[(size_t)k * 128 + c] : zv[(size_t)k * 128 + (c - 128)];
        Vt[(size_t)c * 512 + k] = f2bf(v);
    } else {
        const int k = (b - 512) * 4 + (tid >> 6), c = tid & 63;
        Ot[(size_t)c * 1024 + k] = f2bf(ov[(size_t)k * 64 + c]);
        if (b < 576) flags[(size_t)(b - 512) * 256 + tid] = 0u;
    }
}

// ---------------------------------------------------------------------------
// Fused: APL1 GEMM -> publish chunk aggregate (flag+value, decoupled
// lookback) -> poll predecessors -> prefix -> in-LDS z-mix scan (ht) ->
// APL2 GEMM (y).  512 blocks x 256 threads, 2 blocks/CU (all resident).
// ---------------------------------------------------------------------------
__global__ __launch_bounds__(256, 2) void fused_all(
    const float* __restrict__ x, const float* __restrict__ h0,
    const unsigned short* __restrict__ Vt, const unsigned short* __restrict__ Ot,
    float* __restrict__ agg, unsigned int* __restrict__ flags,
    float* __restrict__ ht_out, float* __restrict__ y)
{
    __shared__ unsigned char smem[LDSSZ];
    const int tid = threadIdx.x;
    const int wave = tid >> 6, lane = tid & 63;
    const int g = blockIdx.x;            // chunk id
    const int n0 = g * RPB;
    const int b = g >> 6, lb = g & 63;   // batch, local chunk (lb preds)

    // ---------------- Phase A: C(64 x 256) = W(64 x 512) x Vt^T -------------
    // preload this thread's 16 x-values (thread = (n = tid>>2, ib = tid&3))
    float xs[16];
    {
        const float* xp = x + (size_t)(n0 + (tid >> 2)) * II + (tid & 3);
        #pragma unroll
        for (int c = 0; c < 16; ++c) xs[c] = xp[4 * c];
    }

    auto stageVt = [&](int c, int bi) {
        unsigned char* buf = smem + VTBUF + bi * 16384;
        #pragma unroll
        for (int j = 0; j < 4; ++j) {
            const int r0 = wave * 64 + j * 16;
            const int r = r0 + (lane >> 2);
            const int ug = (lane & 3) ^ ((r >> 2) & 3);
            gload_lds16((const unsigned char*)Vt + (size_t)r * 1024 + c * 64 + ug * 16,
                        buf + r0 * 64);
        }
    };
    auto buildW = [&](int c, int bi) {
        const int n = tid >> 2, ib = tid & 3;
        uint4 w = apl_w_pack(xs[c]);
        *(uint4*)(smem + WBUF + bi * 5120 + n * 80 + ib * 16) = w;   // padded, no XOR
    };

    const int colbase = wave * 64;       // waves 0,1: h cols; 2,3: z cols
    f32x4 acc[4][4];
    #pragma unroll
    for (int tr = 0; tr < 4; ++tr)
        #pragma unroll
        for (int tc = 0; tc < 4; ++tc)
            acc[tr][tc] = (f32x4){0.f, 0.f, 0.f, 0.f};

    const int u = lane >> 4;             // k-position 0..3 (x8 bf16)

    stageVt(0, 0);
    buildW(0, 0);
    __syncthreads();

    for (int c = 0; c < 16; ++c) {
        if (c < 15) {
            stageVt(c + 1, (c + 1) & 1);
            buildW(c + 1, (c + 1) & 1);
        }
        const int bi = c & 1;
        bf16x8 a[4], bb[4];
        #pragma unroll
        for (int tr = 0; tr < 4; ++tr) {
            const int r = tr * 16 + (lane & 15);
            a[tr] = *(const bf16x8*)(smem + WBUF + bi * 5120 + r * 80 + u * 16);
        }
        #pragma unroll
        for (int tc = 0; tc < 4; ++tc) {
            const int rc = colbase + tc * 16 + (lane & 15);
            bb[tc] = *(const bf16x8*)(smem + VTBUF + bi * 16384 + rc * 64 + ((u ^ ((rc >> 2) & 3)) * 16));
        }
        #pragma unroll
        for (int tr = 0; tr < 4; ++tr)
            #pragma unroll
            for (int tc = 0; tc < 4; ++tc)
                acc[tr][tc] = __builtin_amdgcn_mfma_f32_16x16x32_bf16(a[tr], bb[tc], acc[tr][tc], 0, 0, 0);
        __syncthreads();
    }

    // aggregates (waves 0,1 hold h cols 0..127) -> publish to global directly
    if (wave < 2) {
        #pragma unroll
        for (int tc = 0; tc < 4; ++tc) {
            float s = 0.0f;
            #pragma unroll
            for (int tr = 0; tr < 4; ++tr) {
                f32x4 v = acc[tr][tc];
                s += v[0] + v[1] + v[2] + v[3];
            }
            s += __shfl_xor(s, 16);
            s += __shfl_xor(s, 32);
            if ((lane >> 4) == 0)
                __hip_atomic_store(&agg[(size_t)g * 128 + colbase + tc * 16 + lane], s,
                                   __ATOMIC_RELAXED, __HIP_MEMORY_SCOPE_AGENT);
        }
    }

    // panels: C/D layout col=lane&15 (+tile), row=(lane>>4)*4+reg (+tile)
    #pragma unroll
    for (int tr = 0; tr < 4; ++tr) {
        #pragma unroll
        for (int tc = 0; tc < 4; ++tc) {
            const int col = colbase + tc * 16 + (lane & 15);
            const int r0 = tr * 16 + (lane >> 4) * 4;
            f32x4 v = acc[tr][tc];
            ushort4 p4;
            if (col < 128) {
                p4.x = f2bf(v[0]); p4.y = f2bf(v[1]);
                p4.z = f2bf(v[2]); p4.w = f2bf(v[3]);
                *(ushort4*)(smem + PAN_H + col * 136 + r0 * 2) = p4;
            } else {
                p4.x = f2bf(1.0f / (1.0f + __expf(-v[0])));
                p4.y = f2bf(1.0f / (1.0f + __expf(-v[1])));
                p4.z = f2bf(1.0f / (1.0f + __expf(-v[2])));
                p4.w = f2bf(1.0f / (1.0f + __expf(-v[3])));
                *(ushort4*)(smem + PAN_Z + (col - 128) * 136 + r0 * 2) = p4;
            }
        }
    }

    __syncthreads();                     // agg stores + panel writes drained
    if (tid == 0) {
        __threadfence();
        __hip_atomic_store(&flags[(size_t)g * 32], 1u,
                           __ATOMIC_RELEASE, __HIP_MEMORY_SCOPE_AGENT);
    }

    // kick off Ot chunk-0 DMA (overlaps poll/prefix/scan)
    #pragma unroll
    for (int j = 0; j < 2; ++j) {
        const int r0 = wave * 16 + j * 8;
        const int r = r0 + (lane >> 3);
        const int ug = (lane & 7) ^ (r & 7);
        gload_lds16((const unsigned char*)Ot + (size_t)r * 2048 + ug * 16,
                    smem + OT0 + r0 * 128);
    }

    // ---------- decoupled lookback: parallel poll of same-batch preds -------
    if (tid < lb) {
        const unsigned int* fp = flags + (size_t)(b * 64 + tid) * 32;
        while (__hip_atomic_load(fp, __ATOMIC_ACQUIRE, __HIP_MEMORY_SCOPE_AGENT) == 0u)
            __builtin_amdgcn_s_sleep(1);
    }
    __syncthreads();                     // all preds done; OT0 DMA drained

    // ---------------- prefix + in-LDS z-mix scan -> ht ----------------------
    if (tid < 128) {
        const int d = tid;
        float run = h0[(size_t)b * 128 + d];
        const float* ap = agg + (size_t)(b * 64) * 128 + d;
        float s0 = 0.f, s1 = 0.f, s2 = 0.f, s3 = 0.f;
        int k = 0;
        for (; k + 4 <= lb; k += 4) {
            s0 += __hip_atomic_load(ap + (size_t)(k + 0) * 128, __ATOMIC_RELAXED, __HIP_MEMORY_SCOPE_AGENT);
            s1 += __hip_atomic_load(ap + (size_t)(k + 1) * 128, __ATOMIC_RELAXED, __HIP_MEMORY_SCOPE_AGENT);
            s2 += __hip_atomic_load(ap + (size_t)(k + 2) * 128, __ATOMIC_RELAXED, __HIP_MEMORY_SCOPE_AGENT);
            s3 += __hip_atomic_load(ap + (size_t)(k + 3) * 128, __ATOMIC_RELAXED, __HIP_MEMORY_SCOPE_AGENT);
        }
        for (; k < lb; ++k)
            s0 += __hip_atomic_load(ap + (size_t)k * 128, __ATOMIC_RELAXED, __HIP_MEMORY_SCOPE_AGENT);
        run += (s0 + s1) + (s2 + s3);
        #pragma unroll
        for (int rq = 0; rq < 16; ++rq) {
            ushort4 h4 = *(const ushort4*)(smem + PAN_H + d * 136 + rq * 8);
            ushort4 z4 = *(const ushort4*)(smem + PAN_Z + d * 136 + rq * 8);
            const unsigned short* hp = (const unsigned short*)&h4;
            const unsigned short* zp = (const unsigned short*)&z4;
            #pragma unroll
            for (int kk = 0; kk < 4; ++kk) {
                const int r = rq * 4 + kk;
                float hb = bf2f(hp[kk]);
                float zt = bf2f(zp[kk]);
                run += hb;
                float htv = (1.0f - zt) * run + zt * hb;
                ht_out[(size_t)(n0 + r) * DD + d] = htv;
                *(unsigned short*)(smem + HTB + r * 264 + d * 2) = f2bf(htv);  // 264-B stride!
            }
        }
    }
    __syncthreads();                     // htb ready; panels dead

    // ---------------- Phase C: y(64 x 64) = W2(64 x 1024) x Ot^T ------------
    auto stageOt = [&](int c, unsigned char* buf) {
        #pragma unroll
        for (int j = 0; j < 2; ++j) {
            const int r0 = wave * 16 + j * 8;
            const int r = r0 + (lane >> 3);
            const int ug = (lane & 7) ^ (r & 7);
            gload_lds16((const unsigned char*)Ot + (size_t)r * 2048 + c * 128 + ug * 16,
                        buf + r0 * 128);
        }
    };
    auto buildW2 = [&](int c, int bi) {
        unsigned char* wb = smem + W2BUF + bi * 8192;
        const int n = tid >> 2, dl2 = tid & 3;
        unsigned int pair = *(const unsigned int*)(smem + HTB + n * 264 + (c * 8 + 2 * dl2) * 2);
        uint4 w0 = apl_w_pack(bf2f((unsigned short)(pair & 0xffffu)));
        uint4 w1 = apl_w_pack(bf2f((unsigned short)(pair >> 16)));
        *(uint4*)(wb + n * 128 + (((2 * dl2)     ^ (n & 7)) * 16)) = w0;
        *(uint4*)(wb + n * 128 + (((2 * dl2 + 1) ^ (n & 7)) * 16)) = w1;
    };

    buildW2(0, 0);
    __syncthreads();

    const int wr = wave >> 1, wc = wave & 1;
    f32x4 acc2[2][2];
    #pragma unroll
    for (int tr = 0; tr < 2; ++tr)
        #pragma unroll
        for (int tc = 0; tc < 2; ++tc)
            acc2[tr][tc] = (f32x4){0.f, 0.f, 0.f, 0.f};

    for (int c = 0; c < 16; ++c) {
        if (c < 15) {
            stageOt(c + 1, smem + (((c + 1) & 1) ? OT1 : OT0));
            buildW2(c + 1, (c + 1) & 1);
        }
        unsigned char* wb = smem + W2BUF + (c & 1) * 8192;
        unsigned char* ob = smem + ((c & 1) ? OT1 : OT0);
        #pragma unroll
        for (int s = 0; s < 2; ++s) {
            const int pos = s * 4 + (lane >> 4);
            bf16x8 a2[2], b2[2];
            #pragma unroll
            for (int tr = 0; tr < 2; ++tr) {
                const int r = wr * 32 + tr * 16 + (lane & 15);
                a2[tr] = *(const bf16x8*)(wb + r * 128 + ((pos ^ (r & 7)) * 16));
            }
            #pragma unroll
            for (int tc = 0; tc < 2; ++tc) {
                const int rc = wc * 32 + tc * 16 + (lane & 15);
                b2[tc] = *(const bf16x8*)(ob + rc * 128 + ((pos ^ (rc & 7)) * 16));
            }
            #pragma unroll
            for (int tr = 0; tr < 2; ++tr)
                #pragma unroll
                for (int tc = 0; tc < 2; ++tc)
                    acc2[tr][tc] = __builtin_amdgcn_mfma_f32_16x16x32_bf16(a2[tr], b2[tc], acc2[tr][tc], 0, 0, 0);
        }
        __syncthreads();
    }

    #pragma unroll
    for (int tr = 0; tr < 2; ++tr)
        #pragma unroll
        for (int tc = 0; tc < 2; ++tc) {
            const int col = wc * 32 + tc * 16 + (lane & 15);
            const int n = n0 + wr * 32 + tr * 16 + (lane >> 4) * 4;
            f32x4 v = acc2[tr][tc];
            #pragma unroll
            for (int rg = 0; rg < 4; ++rg)
                y[(size_t)(n + rg) * OO + col] = v[rg];
        }
}

// ---------------------------------------------------------------------------
extern "C" void kernel_launch(void* const* d_in, const int* in_sizes, int n_in,
                              void* d_out, int out_size, void* d_ws, size_t ws_size,
                              hipStream_t stream) {
    const float* x  = (const float*)d_in[0];   // (B,T,I)
    const float* h0 = (const float*)d_in[1];   // (B,D)
    const float* zv = (const float*)d_in[2];   // (I,P,D)
    const float* hv = (const float*)d_in[3];   // (I,P,D)
    const float* ov = (const float*)d_in[4];   // (D,P,O)

    float* y  = (float*)d_out;                           // (B,T,O)
    float* ht = (float*)d_out + (size_t)NTOT * OO;       // (B,T,D)

    unsigned int* flags = (unsigned int*)d_ws;                     // 512*32 u32 = 64 KB
    float* agg = (float*)(flags + (size_t)NBLK * 32);              // 512*128 f32 = 256 KB
    unsigned short* Vt = (unsigned short*)(agg + (size_t)NBLK * 128);  // 256x512
    unsigned short* Ot = Vt + 256 * 512;                               // 64x1024

    prep_tables<<<768, 256, 0, stream>>>(hv, zv, ov, Vt, Ot, flags);
    fused_all<<<NBLK, 256, 0, stream>>>(x, h0, Vt, Ot, agg, flags, ht, y);
}